// Round 3
// baseline (127.504 us; speedup 1.0000x reference)
//
#include <hip/hip_runtime.h>
#include <hip/hip_fp16.h>
#include <math.h>

#define NA_ 10000
#define NM_ 150000
#define B_  4
#define NS_ 4
#define NMAX_ 32
#define NO_ 4
#define H1_ 4
#define H2_ 38
#define PI_F 3.14159265358979323846f

// ---- precompute-path ws layout (all 16B aligned) ----
#define REC_OFF   ((size_t)0)
#define REC_BYTES ((size_t)B_ * NM_ * 16)            // 9,600,000
#define CSN_OFF   (REC_OFF + REC_BYTES)
#define CSN_BYTES ((size_t)B_ * NA_ * NMAX_ * 4)     // 5,120,000
#define R_OFF     (CSN_OFF + CSN_BYTES)
#define R_BYTES   ((size_t)B_ * NM_ * NMAX_ * 2)     // 38,400,000
#define ST_OFF    (R_OFF + R_BYTES)
#define ST_BYTES  ((size_t)B_ * (NA_ + 1) * 4 + 16)
#define WS_NEED   (ST_OFF + ST_BYTES)

// ---------------------------------------------------------------------------
// Kernel 0: segment starts from sorted iidx.
// ---------------------------------------------------------------------------
__global__ void starts_kernel(const int* __restrict__ iidx, int* __restrict__ starts) {
    int p = blockIdx.x * blockDim.x + threadIdx.x;
    if (p >= B_ * NM_) return;
    int b = p / NM_, pl = p - b * NM_;
    const int* ii = iidx + (size_t)b * NM_;
    int* st = starts + (size_t)b * (NA_ + 1);
    int cur = ii[pl];
    int prev = (pl == 0) ? -1 : ii[pl - 1];
    for (int a = prev + 1; a <= cur; ++a) st[a] = pl;
    if (pl == NM_ - 1) {
        for (int a = cur + 1; a <= NA_; ++a) st[a] = NM_;
    }
}

// ---------------------------------------------------------------------------
// Prep: fully parallel over (b, p, n). R[b][p][n] = fcut*exp(alpha*(d-rs)^2)
// (fp16), and per-pair record rec = (x, y, z, bitcast j).
// ---------------------------------------------------------------------------
__global__ __launch_bounds__(256) void prep_kernel(
    const float* __restrict__ disp, const float* __restrict__ alpha,
    const float* __restrict__ rsp, const int* __restrict__ jidx,
    const int* __restrict__ sorted_numbers,
    __half* __restrict__ R, float4* __restrict__ rec)
{
    int idx = blockIdx.x * 256 + threadIdx.x;     // p*32+n within image
    if (idx >= NM_ * NMAX_) return;
    int b = blockIdx.y;
    int n = idx & 31, p = idx >> 5;
    size_t gp = (size_t)b * NM_ + p;
    int j = jidx[gp];
    int jat = sorted_numbers[j];
    float x = disp[gp * 3 + 0];
    float y = disp[gp * 3 + 1];
    float z = disp[gp * 3 + 2];
    float dist = sqrtf(x * x + y * y + z * z);
    float c = __cosf(dist * (PI_F / 6.0f));
    float fc = 0.25f * (c + 1.f) * (c + 1.f);
    float av = alpha[jat * NMAX_ + n];
    float rsv = rsp[jat * NMAX_ + n];
    float dd = dist - rsv;
    R[gp * NMAX_ + n] = __float2half(fc * __expf(av * dd * dd));
    if (n == 0) rec[gp] = make_float4(x, y, z, __int_as_float(j));
}

// ---------------------------------------------------------------------------
// Main pass (precomputed path): one wave = TWO atoms (one per 32-lane half).
// Inner loop: rec (dwordx4) + R (fp16) + dep gather, 5 fma-ish VALU.
// Prefetch: rec/R at distance 2, dep at distance 1, all clamped (branchless).
// ---------------------------------------------------------------------------
template <int PASS>
__global__ __launch_bounds__(256) void pass_kernel(
    const __half* __restrict__ R, const float4* __restrict__ rec,
    const float* __restrict__ spp, const float* __restrict__ op,
    const float* __restrict__ w1, const float* __restrict__ b1,
    const float* __restrict__ w2, const float* __restrict__ b2,
    const float* __restrict__ w3, const float* __restrict__ b3,
    const int* __restrict__ sorted_numbers, const int* __restrict__ starts,
    float* __restrict__ csn2, float* __restrict__ out)
{
    int wave = blockIdx.x * 4 + (threadIdx.x >> 6);
    int lane = threadIdx.x & 63;
    int h = lane >> 5;
    int n = lane & 31;
    int g = wave * 2 + h;                 // b*NA + a
    if (g >= B_ * NA_) return;
    int b = g / NA_, a = g - b * NA_;

    float spv[NS_];
    if constexpr (PASS == 0) {
#pragma unroll
        for (int s = 0; s < NS_; ++s) spv[s] = spp[s * NMAX_ + n];
    }

    const float* opb = op + (size_t)PASS * 2 * NMAX_ * NO_;
    float W0[NO_], W1[NO_];
#pragma unroll
    for (int o = 0; o < NO_; ++o) {
        W0[o] = opb[(0 * NMAX_ + n) * NO_ + o];
        W1[o] = opb[(1 * NMAX_ + n) * NO_ + o];
    }

    const int* st = starts + b * (NA_ + 1);
    int p0 = st[a], p1 = st[a + 1];
    const __half* Rb = R + (size_t)b * NM_ * NMAX_;
    const float4* rb = rec + (size_t)b * NM_;
    const float* csb = csn2 + (size_t)b * NA_ * NMAX_;

    float acc0 = 0.f, acc1 = 0.f, acc2 = 0.f, acc3 = 0.f;

    if (p0 < p1) {
        int last = p1 - 1;
        // stage A (p0) fully, stage B (p0+1) rec+R
        float4 recA = rb[p0];
        float RA = __half2float(Rb[(size_t)p0 * NMAX_ + n]);
        int jA = __float_as_int(recA.w);
        int jatA = 0; float cjA = 0.f;
        if constexpr (PASS == 0) jatA = sorted_numbers[jA];
        else cjA = csb[(size_t)jA * NMAX_ + n];
        int pB = (p0 + 1 < last) ? p0 + 1 : last;
        float4 recB = rb[pB];
        float RB = __half2float(Rb[(size_t)pB * NMAX_ + n]);

        for (int p = p0; p <= last; ++p) {
            int pn2 = (p + 2 < last) ? p + 2 : last;
            // prefetch rec/R for p+2, dep for p+1 (addr from recB)
            float4 recC = rb[pn2];
            float RC = __half2float(Rb[(size_t)pn2 * NMAX_ + n]);
            int jB = __float_as_int(recB.w);
            int jatB = 0; float cjB = 0.f;
            if constexpr (PASS == 0) jatB = sorted_numbers[jB];
            else cjB = csb[(size_t)jB * NMAX_ + n];

            // compute with stage A
            float cj;
            if constexpr (PASS == 0) {
                bool s0 = (jatA & 1) != 0, s1 = (jatA & 2) != 0;
                cj = s1 ? (s0 ? spv[3] : spv[2]) : (s0 ? spv[1] : spv[0]);
            } else {
                cj = cjA;
            }
            float coef = RA * cj;
            acc0 += coef;
            acc1 = fmaf(coef, recA.x, acc1);
            acc2 = fmaf(coef, recA.y, acc2);
            acc3 = fmaf(coef, recA.z, acc3);

            // rotate
            recA = recB; recB = recC;
            RA = RB; RB = RC;
            if constexpr (PASS == 0) jatA = jatB; else cjA = cjB;
        }
    }

    // t[l][o] butterfly over the 32-lane half
    float t[4][NO_];
#pragma unroll
    for (int o = 0; o < NO_; ++o) {
        t[0][o] = W0[o] * acc0;
        t[1][o] = W1[o] * acc1;
        t[2][o] = W1[o] * acc2;
        t[3][o] = W1[o] * acc3;
    }
#pragma unroll
    for (int off = 1; off < 32; off <<= 1) {
#pragma unroll
        for (int l = 0; l < 4; ++l)
#pragma unroll
            for (int o = 0; o < NO_; ++o)
                t[l][o] += __shfl_xor(t[l][o], off);
    }
    float rho[NO_];
#pragma unroll
    for (int o = 0; o < NO_; ++o)
        rho[o] = t[0][o] * t[0][o] + t[1][o] * t[1][o] +
                 t[2][o] * t[2][o] + t[3][o] * t[3][o];

    if constexpr (PASS == 1) {
        if (n == 0) {
            *reinterpret_cast<float4*>(out + (size_t)g * NO_) =
                make_float4(rho[0], rho[1], rho[2], rho[3]);
        }
    } else {
        float h1v[H1_];
#pragma unroll
        for (int k = 0; k < H1_; ++k) {
            float s = b1[k];
#pragma unroll
            for (int o = 0; o < NO_; ++o) s = fmaf(rho[o], w1[o * H1_ + k], s);
            h1v[k] = tanhf(s);
        }
        float sa = b2[n];
        int jbi = 32 + (n < 6 ? n : 5);
        float sb = b2[jbi];
#pragma unroll
        for (int k = 0; k < H1_; ++k) {
            sa = fmaf(h1v[k], w2[k * H2_ + n], sa);
            sb = fmaf(h1v[k], w2[k * H2_ + jbi], sb);
        }
        float hva = tanhf(sa);
        float hvb = tanhf(sb);
        float on = b3[n];
        int base_lane = h << 5;
#pragma unroll
        for (int j2 = 0; j2 < 32; ++j2) {
            float hj = __shfl(hva, base_lane + j2);
            on = fmaf(hj, w3[j2 * NMAX_ + n], on);
        }
#pragma unroll
        for (int j2 = 0; j2 < 6; ++j2) {
            float hj = __shfl(hvb, base_lane + j2);
            on = fmaf(hj, w3[(32 + j2) * NMAX_ + n], on);
        }
        int aat = sorted_numbers[a];
        bool t0b = (aat & 1) != 0, t1b = (aat & 2) != 0;
        float basev = t1b ? (t0b ? spv[3] : spv[2]) : (t0b ? spv[1] : spv[0]);
        csn2[(size_t)g * NMAX_ + n] = basev + on;
    }
}

// ---------------------------------------------------------------------------
// Fallback pass kernel (round-2 proven code) — used if ws_size is too small
// for the precompute buffers.
// ---------------------------------------------------------------------------
template <int PASS>
__global__ __launch_bounds__(256) void fb_pass_kernel(
    const float* __restrict__ disp, const float* __restrict__ alpha,
    const float* __restrict__ rsp, const float* __restrict__ spp,
    const float* __restrict__ op, const float* __restrict__ w1,
    const float* __restrict__ b1, const float* __restrict__ w2,
    const float* __restrict__ b2, const float* __restrict__ w3,
    const float* __restrict__ b3, const int* __restrict__ jidx,
    const int* __restrict__ sorted_numbers, const int* __restrict__ starts,
    float* __restrict__ csn2, float* __restrict__ out)
{
    int wave = blockIdx.x * 4 + (threadIdx.x >> 6);
    int lane = threadIdx.x & 63;
    int h = lane >> 5;
    int n = lane & 31;
    int g = wave * 2 + h;
    if (g >= B_ * NA_) return;
    int b = g / NA_, a = g - b * NA_;

    float al[NS_], rv[NS_], spv[NS_];
#pragma unroll
    for (int s = 0; s < NS_; ++s) {
        al[s] = alpha[s * NMAX_ + n];
        rv[s] = rsp[s * NMAX_ + n];
        spv[s] = spp[s * NMAX_ + n];
    }
    const float* opb = op + (size_t)PASS * 2 * NMAX_ * NO_;
    float W0[NO_], W1[NO_];
#pragma unroll
    for (int o = 0; o < NO_; ++o) {
        W0[o] = opb[(0 * NMAX_ + n) * NO_ + o];
        W1[o] = opb[(1 * NMAX_ + n) * NO_ + o];
    }
    const int* st = starts + b * (NA_ + 1);
    int p0 = st[a], p1 = st[a + 1];
    const int* jjb = jidx + (size_t)b * NM_;
    const float* dpb = disp + (size_t)b * NM_ * 3;
    const float* csb = csn2 + (size_t)b * NA_ * NMAX_;

    float acc0 = 0.f, acc1 = 0.f, acc2 = 0.f, acc3 = 0.f;
    for (int p = p0; p < p1; ++p) {
        int j = jjb[p];
        float x = dpb[p * 3 + 0], y = dpb[p * 3 + 1], z = dpb[p * 3 + 2];
        float dist = sqrtf(x * x + y * y + z * z);
        float c = __cosf(dist * (PI_F / 6.0f));
        float fcv = 0.25f * (c + 1.f) * (c + 1.f);
        int jat = sorted_numbers[j];
        bool s0 = (jat & 1) != 0, s1 = (jat & 2) != 0;
        float av = s1 ? (s0 ? al[3] : al[2]) : (s0 ? al[1] : al[0]);
        float rsv = s1 ? (s0 ? rv[3] : rv[2]) : (s0 ? rv[1] : rv[0]);
        float cj;
        if constexpr (PASS == 0)
            cj = s1 ? (s0 ? spv[3] : spv[2]) : (s0 ? spv[1] : spv[0]);
        else
            cj = csb[(size_t)j * NMAX_ + n];
        float dd = dist - rsv;
        float coef = fcv * cj * __expf(av * dd * dd);
        acc0 += coef;
        acc1 = fmaf(coef, x, acc1);
        acc2 = fmaf(coef, y, acc2);
        acc3 = fmaf(coef, z, acc3);
    }
    float t[4][NO_];
#pragma unroll
    for (int o = 0; o < NO_; ++o) {
        t[0][o] = W0[o] * acc0; t[1][o] = W1[o] * acc1;
        t[2][o] = W1[o] * acc2; t[3][o] = W1[o] * acc3;
    }
#pragma unroll
    for (int off = 1; off < 32; off <<= 1) {
#pragma unroll
        for (int l = 0; l < 4; ++l)
#pragma unroll
            for (int o = 0; o < NO_; ++o)
                t[l][o] += __shfl_xor(t[l][o], off);
    }
    float rho[NO_];
#pragma unroll
    for (int o = 0; o < NO_; ++o)
        rho[o] = t[0][o] * t[0][o] + t[1][o] * t[1][o] +
                 t[2][o] * t[2][o] + t[3][o] * t[3][o];
    if constexpr (PASS == 1) {
        if (n == 0)
            *reinterpret_cast<float4*>(out + (size_t)g * NO_) =
                make_float4(rho[0], rho[1], rho[2], rho[3]);
    } else {
        float h1v[H1_];
#pragma unroll
        for (int k = 0; k < H1_; ++k) {
            float s = b1[k];
#pragma unroll
            for (int o = 0; o < NO_; ++o) s = fmaf(rho[o], w1[o * H1_ + k], s);
            h1v[k] = tanhf(s);
        }
        float sa = b2[n];
        int jbi = 32 + (n < 6 ? n : 5);
        float sb = b2[jbi];
#pragma unroll
        for (int k = 0; k < H1_; ++k) {
            sa = fmaf(h1v[k], w2[k * H2_ + n], sa);
            sb = fmaf(h1v[k], w2[k * H2_ + jbi], sb);
        }
        float hva = tanhf(sa), hvb = tanhf(sb);
        float on = b3[n];
        int base_lane = h << 5;
#pragma unroll
        for (int j2 = 0; j2 < 32; ++j2)
            on = fmaf(__shfl(hva, base_lane + j2), w3[j2 * NMAX_ + n], on);
#pragma unroll
        for (int j2 = 0; j2 < 6; ++j2)
            on = fmaf(__shfl(hvb, base_lane + j2), w3[(32 + j2) * NMAX_ + n], on);
        int aat = sorted_numbers[a];
        bool t0b = (aat & 1) != 0, t1b = (aat & 2) != 0;
        float basev = t1b ? (t0b ? spv[3] : spv[2]) : (t0b ? spv[1] : spv[0]);
        csn2[(size_t)g * NMAX_ + n] = basev + on;
    }
}

extern "C" void kernel_launch(void* const* d_in, const int* in_sizes, int n_in,
                              void* d_out, int out_size, void* d_ws, size_t ws_size,
                              hipStream_t stream) {
    const float* disp = (const float*)d_in[0];
    const float* alpha = (const float*)d_in[1];
    const float* rsp = (const float*)d_in[2];
    const float* spp = (const float*)d_in[3];
    const float* op = (const float*)d_in[4];
    const float* w1 = (const float*)d_in[5];
    const float* b1 = (const float*)d_in[6];
    const float* w2 = (const float*)d_in[7];
    const float* b2 = (const float*)d_in[8];
    const float* w3 = (const float*)d_in[9];
    const float* b3 = (const float*)d_in[10];
    const int* iidx = (const int*)d_in[11];
    const int* jidx = (const int*)d_in[12];
    const int* sn = (const int*)d_in[13];
    float* out = (float*)d_out;

    int nthr = B_ * NM_;
    int nwaves = (B_ * NA_) / 2;
    int nblocks = (nwaves + 3) / 4;

    if (ws_size >= WS_NEED) {
        float4* rec = (float4*)((char*)d_ws + REC_OFF);
        float* csn2 = (float*)((char*)d_ws + CSN_OFF);
        __half* R = (__half*)((char*)d_ws + R_OFF);
        int* starts = (int*)((char*)d_ws + ST_OFF);

        starts_kernel<<<(nthr + 255) / 256, 256, 0, stream>>>(iidx, starts);
        dim3 pgrid((NM_ * NMAX_ + 255) / 256, B_);
        prep_kernel<<<pgrid, 256, 0, stream>>>(disp, alpha, rsp, jidx, sn, R, rec);
        pass_kernel<0><<<nblocks, 256, 0, stream>>>(R, rec, spp, op, w1, b1, w2,
                                                    b2, w3, b3, sn, starts, csn2, out);
        pass_kernel<1><<<nblocks, 256, 0, stream>>>(R, rec, spp, op, w1, b1, w2,
                                                    b2, w3, b3, sn, starts, csn2, out);
    } else {
        float* csn2 = (float*)d_ws;
        int* starts = (int*)((char*)d_ws + CSN_BYTES);
        starts_kernel<<<(nthr + 255) / 256, 256, 0, stream>>>(iidx, starts);
        fb_pass_kernel<0><<<nblocks, 256, 0, stream>>>(disp, alpha, rsp, spp, op,
                                                       w1, b1, w2, b2, w3, b3,
                                                       jidx, sn, starts, csn2, out);
        fb_pass_kernel<1><<<nblocks, 256, 0, stream>>>(disp, alpha, rsp, spp, op,
                                                       w1, b1, w2, b2, w3, b3,
                                                       jidx, sn, starts, csn2, out);
    }
}